// Round 1
// baseline (665.479 us; speedup 1.0000x reference)
//
#include <hip/hip_runtime.h>
#include <math.h>

#define SCALE 0.17677669529663687f  /* (256/8)^-0.5 */

// ---------------------------------------------------------------------------
// token row -> spatial row index ((b*56+h)*56+w) for windowed row m in [0,25088)
// m = ((b*64)+s)*49 + tok ; h=(s/8)*7+tok/7 ; w=(s%8)*7+tok%7
__device__ __forceinline__ int token_row_addr(int m) {
    int b = m / 3136;
    int rem = m - b * 3136;
    int s = rem / 49;
    int tok = rem - s * 49;
    int h = (s >> 3) * 7 + tok / 7;
    int w = (s & 7) * 7 + (tok % 7);
    return (b * 56 + h) * 56 + w;
}

// ---------------------------------------------------------------------------
// K0a: per-region mean over the 49 window tokens. grid 512 (b*64+s), block 256 (=c)
__global__ void k_region_mean(const float* __restrict__ x, float* __restrict__ xr) {
    int blk = blockIdx.x;
    int b = blk >> 6, s = blk & 63;
    int c = threadIdx.x;
    int hy0 = (s >> 3) * 7, wx0 = (s & 7) * 7;
    const float* xb = x + ((size_t)b * 56 * 56) * 256 + c;
    float sum = 0.f;
#pragma unroll 1
    for (int t = 0; t < 49; ++t) {
        int h = hy0 + t / 7, w = wx0 + (t % 7);
        sum += xb[(size_t)(h * 56 + w) * 256];
    }
    xr[(size_t)blk * 256 + c] = sum * (1.0f / 49.0f);
}

// ---------------------------------------------------------------------------
// K0b: qkv_r = x_region @ w_qkv + b_qkv. grid 512, block 256.
__global__ void k_region_qkv(const float* __restrict__ xr, const float* __restrict__ wqkv,
                             const float* __restrict__ bqkv, float* __restrict__ qkvr) {
    __shared__ float xs[256];
    int blk = blockIdx.x;
    int t = threadIdx.x;
    xs[t] = xr[(size_t)blk * 256 + t];
    __syncthreads();
    float a0 = 0.f, a1 = 0.f, a2 = 0.f;
#pragma unroll 4
    for (int k = 0; k < 256; ++k) {
        float xv = xs[k];
        const float* wrow = wqkv + (size_t)k * 768;
        a0 += xv * wrow[t];
        a1 += xv * wrow[t + 256];
        a2 += xv * wrow[t + 512];
    }
    float* o = qkvr + (size_t)blk * 768;
    o[t]       = a0 + bqkv[t];
    o[t + 256] = a1 + bqkv[t + 256];
    o[t + 512] = a2 + bqkv[t + 512];
}

// ---------------------------------------------------------------------------
// K0c: sigma = softplus(relu(q_r@w_g1+b_g1)@w_g2+b_g2)+0.5. grid 512, block 64.
__global__ void k_gating(const float* __restrict__ qkvr, const float* __restrict__ wg1,
                         const float* __restrict__ bg1, const float* __restrict__ wg2,
                         const float* __restrict__ bg2, float* __restrict__ sig) {
    __shared__ float hs[64];
    int blk = blockIdx.x;
    int j = threadIdx.x;
    const float* qr = qkvr + (size_t)blk * 768;  // q part
    float acc = bg1[j];
#pragma unroll 4
    for (int k = 0; k < 256; ++k) acc += qr[k] * wg1[(size_t)k * 64 + j];
    hs[j] = fmaxf(acc, 0.f);
    __syncthreads();
    if (j < 2) {
        float gp = bg2[j];
#pragma unroll 1
        for (int m = 0; m < 64; ++m) gp += hs[m] * wg2[m * 2 + j];
        // softplus = max(x,0) + log1p(exp(-|x|))
        float sp = fmaxf(gp, 0.f) + log1pf(expf(-fabsf(gp)));
        sig[blk * 2 + j] = sp + 0.5f;
    }
}

// ---------------------------------------------------------------------------
// K0d: A_r row + top-4 (strict argmax, lower index wins ties) + gaussian weights.
// grid 512 (b*64+s), block 64 (=z).
__global__ void k_topk_gauss(const float* __restrict__ qkvr, const float* __restrict__ sig,
                             int* __restrict__ topk, float* __restrict__ gwt) {
    __shared__ float A[64];
    __shared__ float G[64];
    __shared__ int idxs[4];
    __shared__ float gsum_s;
    int blk = blockIdx.x;
    int b = blk >> 6, s = blk & 63;
    int z = threadIdx.x;
    const float* qr = qkvr + (size_t)blk * 768;                  // q_r[b,s]
    const float* kr = qkvr + (size_t)(b * 64 + z) * 768 + 256;   // k_r[b,z]
    float acc = 0.f;
#pragma unroll 4
    for (int k = 0; k < 256; k += 4) {
        float4 q4 = *(const float4*)(qr + k);
        float4 k4 = *(const float4*)(kr + k);
        acc += q4.x * k4.x + q4.y * k4.y + q4.z * k4.z + q4.w * k4.w;
    }
    A[z] = acc * SCALE;
    float s0 = sig[blk * 2 + 0], s1 = sig[blk * 2 + 1];
    float dx = (float)((z & 7) - (s & 7));
    float dy = (float)((z >> 3) - (s >> 3));
    float t0 = dx / s0, t1 = dy / s1;
    float zz = t0 * t0 + t1 * t1;
    G[z] = expf(-0.5f * zz);
    __syncthreads();
    if (z == 0) {
        float gs = 0.f;
        for (int m = 0; m < 64; ++m) gs += G[m];
        gsum_s = gs + 1e-6f;
        for (int it = 0; it < 4; ++it) {
            int best = 0;
            float bv = A[0];
            for (int m = 1; m < 64; ++m) {
                if (A[m] > bv) { bv = A[m]; best = m; }
            }
            idxs[it] = best;
            A[best] = -3.0e38f;
        }
    }
    __syncthreads();
    if (z < 4) {
        int id = idxs[z];
        topk[blk * 4 + z] = id;
        gwt[blk * 4 + z] = G[id] / gsum_s;
    }
}

// ---------------------------------------------------------------------------
// K1: big qkv GEMM. M=25088 (windowed gather of x rows), K=256, N=768.
// 64x64 tile, 256 threads, 4x4 micro-tile. Outputs split into Q/K/V (+bias).
__global__ __launch_bounds__(256) void k_qkv_gemm(
    const float* __restrict__ x, const float* __restrict__ wqkv,
    const float* __restrict__ bqkv, float* __restrict__ Q,
    float* __restrict__ Kb, float* __restrict__ V) {
    __shared__ float As[16][68];  // [kk][row], pad 68 (272B rows, 16B aligned)
    __shared__ float Bs[16][68];  // [kk][col]
    int tid = threadIdx.x;
    int n0 = blockIdx.x * 64;
    int m0 = blockIdx.y * 64;
    int ty = tid >> 4, tx = tid & 15;
    int ar = tid >> 2;            // A row 0..63
    int ak = (tid & 3) * 4;       // A k-offset 0,4,8,12
    const float* arow = x + (size_t)token_row_addr(m0 + ar) * 256 + ak;
    int bk = tid >> 4;            // B k-row 0..15
    int bc = (tid & 15) * 4;      // B col 0..60
    const float* bptr = wqkv + (size_t)bk * 768 + n0 + bc;

    float acc[4][4] = {};
#pragma unroll 1
    for (int k0 = 0; k0 < 256; k0 += 16) {
        float4 a4 = *(const float4*)(arow + k0);
        float4 b4 = *(const float4*)(bptr + (size_t)k0 * 768);
        __syncthreads();
        As[ak + 0][ar] = a4.x;
        As[ak + 1][ar] = a4.y;
        As[ak + 2][ar] = a4.z;
        As[ak + 3][ar] = a4.w;
        *(float4*)&Bs[bk][bc] = b4;
        __syncthreads();
#pragma unroll
        for (int kk = 0; kk < 16; ++kk) {
            float4 av4 = *(const float4*)&As[kk][ty * 4];
            float4 bv4 = *(const float4*)&Bs[kk][tx * 4];
            float av[4] = {av4.x, av4.y, av4.z, av4.w};
            float bv[4] = {bv4.x, bv4.y, bv4.z, bv4.w};
#pragma unroll
            for (int i = 0; i < 4; ++i)
#pragma unroll
                for (int j = 0; j < 4; ++j) acc[i][j] += av[i] * bv[j];
        }
    }
    int buf = n0 >> 8;                   // 0=Q 1=K 2=V
    int colbase = (n0 & 255) + tx * 4;
    float* dst = (buf == 0) ? Q : (buf == 1 ? Kb : V);
    float4 bias = *(const float4*)(bqkv + n0 + tx * 4);
#pragma unroll
    for (int i = 0; i < 4; ++i) {
        int m = m0 + ty * 4 + i;
        float4 o;
        o.x = acc[i][0] + bias.x;
        o.y = acc[i][1] + bias.y;
        o.z = acc[i][2] + bias.z;
        o.w = acc[i][3] + bias.w;
        *(float4*)(dst + (size_t)m * 256 + colbase) = o;
    }
}

// ---------------------------------------------------------------------------
// K2: per-window attention + fused dwconv. grid 512 (b*64+s), block 256.
// Phase1: logits L[49][196] (thread j owns key-column j, acc[49] in regs)
// Phase2: row softmax. Phase3: PV (thread c owns channel c) + dwconv, write ATT.
__global__ __launch_bounds__(256) void k_attn(
    const float* __restrict__ Q, const float* __restrict__ Kb, const float* __restrict__ V,
    const int* __restrict__ topk, const float* __restrict__ gwt,
    const float* __restrict__ dwk, const float* __restrict__ dwb,
    float* __restrict__ att) {
    __shared__ float L[49][200];  // row stride 800B (16B aligned)
    int blk = blockIdx.x;
    int b = blk >> 6;
    int tid = threadIdx.x;

    // ---- phase 1: logits ----
    if (tid < 196) {
        int r = tid / 49, tok = tid - r * 49;
        int reg = topk[blk * 4 + r];
        float gw = gwt[blk * 4 + r];
        const float* krow = Kb + ((size_t)(b * 64 + reg) * 49 + tok) * 256;
        const float* qbase = Q + (size_t)blk * 49 * 256;
        float acc[49];
#pragma unroll
        for (int w = 0; w < 49; ++w) acc[w] = 0.f;
#pragma unroll 1
        for (int kc = 0; kc < 256; kc += 8) {
            float4 ka = *(const float4*)(krow + kc);
            float4 kb2 = *(const float4*)(krow + kc + 4);
#pragma unroll
            for (int w = 0; w < 49; ++w) {
                float4 qa = *(const float4*)(qbase + w * 256 + kc);
                float4 qb = *(const float4*)(qbase + w * 256 + kc + 4);
                acc[w] += qa.x * ka.x + qa.y * ka.y + qa.z * ka.z + qa.w * ka.w
                        + qb.x * kb2.x + qb.y * kb2.y + qb.z * kb2.z + qb.w * kb2.w;
            }
        }
        float sg = SCALE * gw;
#pragma unroll
        for (int w = 0; w < 49; ++w) L[w][tid] = acc[w] * sg;
    }
    __syncthreads();

    // ---- phase 2: softmax per row ----
    if (tid < 49) {
        float mx = -3.0e38f;
        for (int j = 0; j < 196; ++j) mx = fmaxf(mx, L[tid][j]);
        float sum = 0.f;
        for (int j = 0; j < 196; ++j) {
            float e = expf(L[tid][j] - mx);
            L[tid][j] = e;
            sum += e;
        }
        float inv = 1.0f / sum;
        for (int j = 0; j < 196; ++j) L[tid][j] *= inv;
    }
    __syncthreads();

    // ---- phase 3: out[w][c] = sum_j p[w][j]*gwt[r(j)]*V[j][c]  (+dwconv) ----
    {
        int c = tid;
        float acc2[49];
#pragma unroll
        for (int w = 0; w < 49; ++w) acc2[w] = 0.f;
        const float* vbase = V + (size_t)(b * 64) * 49 * 256;
#pragma unroll 1
        for (int j = 0; j < 196; j += 4) {
            float vv[4];
#pragma unroll
            for (int e = 0; e < 4; ++e) {
                int jj = j + e;
                int r = jj / 49;
                int tok = jj - r * 49;
                int reg = topk[blk * 4 + r];
                float gw = gwt[blk * 4 + r];
                vv[e] = vbase[((size_t)reg * 49 + tok) * 256 + c] * gw;
            }
#pragma unroll
            for (int w = 0; w < 49; ++w) {
                float4 p4 = *(const float4*)&L[w][j];
                acc2[w] += p4.x * vv[0] + p4.y * vv[1] + p4.z * vv[2] + p4.w * vv[3];
            }
        }

        // dwconv 3x3 SAME within the 7x7 window on V (bias-included v) + write
        const float* vme = V + (size_t)blk * 49 * 256 + c;
        const float* dwkc = dwk + c;
        float dwbias = dwb[c];
        float* outp = att + (size_t)blk * 49 * 256 + c;
#pragma unroll
        for (int w = 0; w < 49; ++w) {
            int ty2 = w / 7, tx2 = w % 7;
            float vd = dwbias;
#pragma unroll
            for (int dy = 0; dy < 3; ++dy) {
                int yy = ty2 + dy - 1;
                if (yy < 0 || yy > 6) continue;
#pragma unroll
                for (int dx = 0; dx < 3; ++dx) {
                    int xx = tx2 + dx - 1;
                    if (xx < 0 || xx > 6) continue;
                    vd += vme[(size_t)(yy * 7 + xx) * 256] * dwkc[(size_t)(dy * 3 + dx) * 256];
                }
            }
            outp[(size_t)w * 256] = acc2[w] + vd;
        }
    }
}

// ---------------------------------------------------------------------------
// K3: projection GEMM. M=25088, K=256, N=256, un-windowed scatter + bias.
__global__ __launch_bounds__(256) void k_proj_gemm(
    const float* __restrict__ att, const float* __restrict__ wp,
    const float* __restrict__ bp, float* __restrict__ out) {
    __shared__ float As[16][68];
    __shared__ float Bs[16][68];
    int tid = threadIdx.x;
    int n0 = blockIdx.x * 64;
    int m0 = blockIdx.y * 64;
    int ty = tid >> 4, tx = tid & 15;
    int ar = tid >> 2;
    int ak = (tid & 3) * 4;
    const float* arow = att + (size_t)(m0 + ar) * 256 + ak;
    int bk = tid >> 4;
    int bc = (tid & 15) * 4;
    const float* bptr = wp + (size_t)bk * 256 + n0 + bc;

    float acc[4][4] = {};
#pragma unroll 1
    for (int k0 = 0; k0 < 256; k0 += 16) {
        float4 a4 = *(const float4*)(arow + k0);
        float4 b4 = *(const float4*)(bptr + (size_t)k0 * 256);
        __syncthreads();
        As[ak + 0][ar] = a4.x;
        As[ak + 1][ar] = a4.y;
        As[ak + 2][ar] = a4.z;
        As[ak + 3][ar] = a4.w;
        *(float4*)&Bs[bk][bc] = b4;
        __syncthreads();
#pragma unroll
        for (int kk = 0; kk < 16; ++kk) {
            float4 av4 = *(const float4*)&As[kk][ty * 4];
            float4 bv4 = *(const float4*)&Bs[kk][tx * 4];
            float av[4] = {av4.x, av4.y, av4.z, av4.w};
            float bv[4] = {bv4.x, bv4.y, bv4.z, bv4.w};
#pragma unroll
            for (int i = 0; i < 4; ++i)
#pragma unroll
                for (int j = 0; j < 4; ++j) acc[i][j] += av[i] * bv[j];
        }
    }
    float4 bias = *(const float4*)(bp + n0 + tx * 4);
#pragma unroll
    for (int i = 0; i < 4; ++i) {
        int m = m0 + ty * 4 + i;
        size_t orow = (size_t)token_row_addr(m);
        float4 o;
        o.x = acc[i][0] + bias.x;
        o.y = acc[i][1] + bias.y;
        o.z = acc[i][2] + bias.z;
        o.w = acc[i][3] + bias.w;
        *(float4*)(out + orow * 256 + n0 + tx * 4) = o;
    }
}

// ---------------------------------------------------------------------------
extern "C" void kernel_launch(void* const* d_in, const int* in_sizes, int n_in,
                              void* d_out, int out_size, void* d_ws, size_t ws_size,
                              hipStream_t stream) {
    const float* x    = (const float*)d_in[0];
    const float* wqkv = (const float*)d_in[1];
    const float* bqkv = (const float*)d_in[2];
    const float* wg1  = (const float*)d_in[3];
    const float* bg1  = (const float*)d_in[4];
    const float* wg2  = (const float*)d_in[5];
    const float* bg2  = (const float*)d_in[6];
    const float* dwk  = (const float*)d_in[7];
    const float* dwb  = (const float*)d_in[8];
    const float* wp   = (const float*)d_in[9];
    const float* bp   = (const float*)d_in[10];
    float* out = (float*)d_out;
    float* ws = (float*)d_ws;

    const size_t NTOT = (size_t)25088 * 256;  // 6,422,528
    float* Q    = ws;
    float* Kbuf = Q + NTOT;
    float* V    = Kbuf + NTOT;
    float* ATT  = V + NTOT;
    float* XR   = ATT + NTOT;          // 512*256
    float* QKVR = XR + 512 * 256;      // 512*768
    float* SIG  = QKVR + 512 * 768;    // 512*2
    float* GWT  = SIG + 1024;          // 512*4
    int*   TOPK = (int*)(GWT + 2048);  // 512*4 ints

    hipLaunchKernelGGL(k_region_mean, dim3(512), dim3(256), 0, stream, x, XR);
    hipLaunchKernelGGL(k_region_qkv, dim3(512), dim3(256), 0, stream, XR, wqkv, bqkv, QKVR);
    hipLaunchKernelGGL(k_gating, dim3(512), dim3(64), 0, stream, QKVR, wg1, bg1, wg2, bg2, SIG);
    hipLaunchKernelGGL(k_topk_gauss, dim3(512), dim3(64), 0, stream, QKVR, SIG, TOPK, GWT);
    hipLaunchKernelGGL(k_qkv_gemm, dim3(12, 392), dim3(256), 0, stream,
                       x, wqkv, bqkv, Q, Kbuf, V);
    hipLaunchKernelGGL(k_attn, dim3(512), dim3(256), 0, stream,
                       Q, Kbuf, V, TOPK, GWT, dwk, dwb, ATT);
    hipLaunchKernelGGL(k_proj_gemm, dim3(4, 392), dim3(256), 0, stream, ATT, wp, bp, out);
}